// Round 1
// baseline (44.343 us; speedup 1.0000x reference)
//
#include <hip/hip_runtime.h>

namespace {
constexpr int kM = 4, kJ = 2, kI = 3, kL = 2, kW = 9;

// d_ws derived-parameter layout (floats):
//   for mj in [0,8): base = mj*9 -> [A, B0, B1, w0, w1, C00, C01, C10, C11]
//   D[m][l] at 72 + m*2 + l      (8 floats)          total: 80 floats
__global__ void prep_kernel(const float* __restrict__ constants,
                            const float* __restrict__ gammas,
                            const float* __restrict__ W_body,
                            const float* __restrict__ b_body,
                            const float* __restrict__ W_head,
                            const float* __restrict__ b_head,
                            float* __restrict__ dp) {
  if (threadIdx.x != 0 || blockIdx.x != 0) return;
  float D[kM][kL];
  for (int m = 0; m < kM; ++m)
    for (int l = 0; l < kL; ++l) D[m][l] = b_head[m * kL + l];
  for (int m = 0; m < kM; ++m) {
    for (int j = 0; j < kJ; ++j) {
      const int mj = m * kJ + j;
      const float g0 = fminf(fmaxf(gammas[mj * kL + 0], 0.f), 1.f);
      const float g1 = fminf(fmaxf(gammas[mj * kL + 1], 0.f), 1.f);
      const float w0 = 1.f - g0, w1 = 1.f - g1;
      const float c0 = constants[mj * kL + 0], c1 = constants[mj * kL + 1];
      const float gavg = 0.5f * (g0 + g1);
      float* p = dp + mj * 9;
      p[0] = w0 * c0 * c0 + w1 * c1 * c1;   // A = sum_l w_l * c_l^2
      p[1] = -2.f * w0 * c0;                // B_l = -2 w_l c_l
      p[2] = -2.f * w1 * c1;
      p[3] = w0;
      p[4] = w1;
      for (int l = 0; l < kL; ++l) {
        for (int lp = 0; lp < kL; ++lp) {
          float acc = 0.f;
          for (int i = 0; i < kI; ++i)
            acc += W_head[(m * kL + l) * kI + i] * W_body[(mj * kI + i) * kL + lp];
          p[5 + l * kL + lp] = gavg * acc;  // C[l][l']
        }
        float accb = 0.f;
        for (int i = 0; i < kI; ++i)
          accb += W_head[(m * kL + l) * kI + i] * b_body[mj * kI + i];
        D[m][l] += gavg * accb;
      }
    }
  }
  for (int m = 0; m < kM; ++m)
    for (int l = 0; l < kL; ++l) dp[72 + m * kL + l] = D[m][l];
}

__global__ __launch_bounds__(256) void algelogic_main(
    const float* __restrict__ state, const float* __restrict__ dp,
    float* __restrict__ out) {
  const int b = blockIdx.x * 256 + threadIdx.x;
  const float* srow = state + (size_t)b * (kW * kL);

  float s0[kW], s1[kW], q0[kW], q1[kW];
#pragma unroll
  for (int w = 0; w < kW; ++w) {
    const float2 v = *reinterpret_cast<const float2*>(srow + 2 * w);
    s0[w] = v.x; s1[w] = v.y;
    q0[w] = v.x * v.x; q1[w] = v.y * v.y;
  }

  float ro0[kM], ro1[kM], conf[kM];
#pragma unroll
  for (int m = 0; m < kM; ++m) {
    float mq = 0.f;
    float r0 = dp[72 + m * 2 + 0];
    float r1 = dp[72 + m * 2 + 1];
#pragma unroll
    for (int j = 0; j < kJ; ++j) {
      const float* p = dp + (m * kJ + j) * 9;
      const float A = p[0], B0 = p[1], B1 = p[2], w0 = p[3], w1 = p[4];
      float ms[kW];
      float msmin = 3.4e38f;
#pragma unroll
      for (int w = 0; w < kW; ++w) {
        const float v = A + B0 * s0[w] + w0 * q0[w] + B1 * s1[w] + w1 * q1[w];
        ms[w] = v;
        msmin = fminf(msmin, v);
      }
      float psum = 0.f, pb0 = 0.f, pb1 = 0.f, pmq = 0.f;
#pragma unroll
      for (int w = 0; w < kW; ++w) {
        const float e = __expf(msmin - ms[w]);   // softmax(-ms): exp(min-ms)
        psum += e;
        pb0 += e * s0[w];
        pb1 += e * s1[w];
        pmq += e * ms[w];
      }
      const float rinv = __builtin_amdgcn_rcpf(psum);
      const float best0 = pb0 * rinv, best1 = pb1 * rinv;
      mq += pmq * rinv;
      r0 += p[5] * best0 + p[6] * best1;
      r1 += p[7] * best0 + p[8] * best1;
    }
    ro0[m] = r0; ro1[m] = r1;
    conf[m] = __expf(-mq);
  }

  float* orow = out + (size_t)b * kW;
#pragma unroll
  for (int w = 0; w < kW; ++w) {
    float acc = 0.f;
#pragma unroll
    for (int m = 0; m < kM; ++m) {
      const float d0 = ro0[m] - s0[w];
      const float d1 = ro1[m] - s1[w];
      acc -= conf[m] * (d0 * d0 + d1 * d1);
    }
    orow[w] = acc;
  }
}
}  // namespace

extern "C" void kernel_launch(void* const* d_in, const int* in_sizes, int n_in,
                              void* d_out, int out_size, void* d_ws, size_t ws_size,
                              hipStream_t stream) {
  const float* state     = (const float*)d_in[0];
  const float* constants = (const float*)d_in[1];
  const float* gammas    = (const float*)d_in[2];
  const float* W_body    = (const float*)d_in[3];
  const float* b_body    = (const float*)d_in[4];
  const float* W_head    = (const float*)d_in[5];
  const float* b_head    = (const float*)d_in[6];
  float* out = (float*)d_out;
  float* dp  = (float*)d_ws;

  const int B = in_sizes[0] / (kW * kL);   // 1048576, divisible by 256

  hipLaunchKernelGGL(prep_kernel, dim3(1), dim3(64), 0, stream,
                     constants, gammas, W_body, b_body, W_head, b_head, dp);
  hipLaunchKernelGGL(algelogic_main, dim3(B / 256), dim3(256), 0, stream,
                     state, dp, out);
}